// Round 1
// baseline (91.338 us; speedup 1.0000x reference)
//
#include <hip/hip_runtime.h>

// E[b] = sum_p decompFE_flat[b,p] / r(b, pair p), pairs = strict lower tri row-major.
// B=2048 batches, N=100 atoms, NC2=4950 pairs.

#define BATCH 2048
#define NATOMS 100
#define NPAIRS 4950
#define BLOCK 256

__global__ __launch_bounds__(BLOCK) void eij_kernel(
    const float* __restrict__ coords,   // [B, N, 3]
    const float* __restrict__ decomp,   // [B, NC2]
    float* __restrict__ out)            // [B, 1]
{
    __shared__ float sx[NATOMS];
    __shared__ float sy[NATOMS];
    __shared__ float sz[NATOMS];
    __shared__ float wave_sums[BLOCK / 64];

    const int b = blockIdx.x;
    const int t = threadIdx.x;

    // Stage this batch's coords into LDS (SoA layout).
    const float* cb = coords + (size_t)b * NATOMS * 3;
    for (int i = t; i < NATOMS; i += BLOCK) {
        sx[i] = cb[i * 3 + 0];
        sy[i] = cb[i * 3 + 1];
        sz[i] = cb[i * 3 + 2];
    }
    __syncthreads();

    const float* db = decomp + (size_t)b * NPAIRS;
    float acc = 0.0f;

    // Coalesced stride-BLOCK sweep over pairs.
    for (int p = t; p < NPAIRS; p += BLOCK) {
        // Decode row-major strict-lower-tri pair index:
        // i = floor((1+sqrt(1+8p))/2), j = p - i(i-1)/2, with integer fixup
        // to guard float rounding.
        int i = (int)((1.0f + sqrtf(8.0f * (float)p + 1.0f)) * 0.5f);
        while (i * (i - 1) / 2 > p) --i;
        while ((i + 1) * i / 2 <= p) ++i;
        const int j = p - i * (i - 1) / 2;

        const float dx = sx[i] - sx[j];
        const float dy = sy[i] - sy[j];
        const float dz = sz[i] - sz[j];
        const float d2 = dx * dx + dy * dy + dz * dz;
        acc += db[p] * rsqrtf(d2);
    }

    // Wave-64 shuffle reduction.
    #pragma unroll
    for (int off = 32; off > 0; off >>= 1)
        acc += __shfl_down(acc, off, 64);

    const int wave = t >> 6;
    const int lane = t & 63;
    if (lane == 0) wave_sums[wave] = acc;
    __syncthreads();

    if (t == 0) {
        float s = 0.0f;
        #pragma unroll
        for (int w = 0; w < BLOCK / 64; ++w) s += wave_sums[w];
        out[b] = s;
    }
}

extern "C" void kernel_launch(void* const* d_in, const int* in_sizes, int n_in,
                              void* d_out, int out_size, void* d_ws, size_t ws_size,
                              hipStream_t stream) {
    const float* coords = (const float*)d_in[0];   // [2048, 100, 3]
    const float* decomp = (const float*)d_in[1];   // [2048, 4950]
    float* out = (float*)d_out;                    // [2048, 1]

    eij_kernel<<<BATCH, BLOCK, 0, stream>>>(coords, decomp, out);
}

// Round 2
// 81.979 us; speedup vs baseline: 1.1142x; 1.1142x over previous
//
#include <hip/hip_runtime.h>

// E[b] = sum_p decompFE_flat[b,p] / r(b, pair p), pairs = strict lower tri row-major.
// B=2048 batches, N=100 atoms, NC2=4950 pairs.
//
// R1: compile-time pair table (no data-dependent while loops) -> fully
// unrolled pair loop, 40 independent loads in flight per thread.
// Coords in LDS as float4 -> ds_read_b128.

#define BATCH 2048
#define NATOMS 100
#define NPAIRS 4950
#define BLOCK 256
#define KMAX 20   // ceil(4950/256)

struct PairTab { unsigned short v[NPAIRS]; };

__host__ __device__ constexpr PairTab make_tab() {
    PairTab t{};
    int p = 0;
    for (int i = 1; i < NATOMS; ++i)
        for (int j = 0; j < i; ++j)
            t.v[p++] = (unsigned short)((i << 8) | j);
    return t;
}

__device__ constexpr PairTab PAIR_TAB = make_tab();

__global__ __launch_bounds__(BLOCK) void eij_kernel(
    const float* __restrict__ coords,   // [B, N, 3]
    const float* __restrict__ decomp,   // [B, NC2]
    float* __restrict__ out)            // [B, 1]
{
    __shared__ float4 satom[NATOMS];
    __shared__ float wave_sums[BLOCK / 64];

    const int b = blockIdx.x;
    const int t = threadIdx.x;

    // Stage this batch's coords into LDS as float4 (xyz + pad).
    const float* cb = coords + (size_t)b * NATOMS * 3;
    if (t < NATOMS) {
        satom[t] = make_float4(cb[t * 3 + 0], cb[t * 3 + 1], cb[t * 3 + 2], 0.0f);
    }
    __syncthreads();

    const float* db = decomp + (size_t)b * NPAIRS;
    float acc = 0.0f;

    // Fully unrolled: no data-dependent control flow, loads hoistable.
    #pragma unroll
    for (int k = 0; k < KMAX; ++k) {
        const int p = t + (k << 8);
        const bool ok = (p < NPAIRS);            // only k==19 is ragged
        const int pp = ok ? p : 0;               // clamp: load stays unconditional
        const float d = db[pp];                  // coalesced dword load
        const unsigned pr = PAIR_TAB.v[pp];      // L1-hot table (shared by all blocks)
        const int i = (int)(pr >> 8);
        const int j = (int)(pr & 255u);
        const float4 ci = satom[i];              // ds_read_b128
        const float4 cj = satom[j];              // ds_read_b128
        const float dx = ci.x - cj.x;
        const float dy = ci.y - cj.y;
        const float dz = ci.z - cj.z;
        const float d2 = dx * dx + dy * dy + dz * dz;
        const float contrib = d * rsqrtf(d2);    // pair (1,0) for clamped lanes: d2>0, finite
        acc += ok ? contrib : 0.0f;
    }

    // Wave-64 shuffle reduction.
    #pragma unroll
    for (int off = 32; off > 0; off >>= 1)
        acc += __shfl_down(acc, off, 64);

    if ((t & 63) == 0) wave_sums[t >> 6] = acc;
    __syncthreads();

    if (t == 0)
        out[b] = wave_sums[0] + wave_sums[1] + wave_sums[2] + wave_sums[3];
}

extern "C" void kernel_launch(void* const* d_in, const int* in_sizes, int n_in,
                              void* d_out, int out_size, void* d_ws, size_t ws_size,
                              hipStream_t stream) {
    const float* coords = (const float*)d_in[0];   // [2048, 100, 3]
    const float* decomp = (const float*)d_in[1];   // [2048, 4950]
    float* out = (float*)d_out;                    // [2048, 1]

    eij_kernel<<<BATCH, BLOCK, 0, stream>>>(coords, decomp, out);
}